// Round 13
// baseline (496.386 us; speedup 1.0000x reference)
//
#include <hip/hip_runtime.h>
#include <stdint.h>

typedef __attribute__((ext_vector_type(8))) short bf16x8;
typedef __attribute__((ext_vector_type(4))) float f32x4;

__device__ __forceinline__ unsigned short f2bf(float f) {
  unsigned int u = __builtin_bit_cast(unsigned int, f);
  u += 0x7FFFu + ((u >> 16) & 1u);
  return (unsigned short)(u >> 16);
}

__device__ __forceinline__ float bf2f(unsigned short s) {
  return __builtin_bit_cast(float, (unsigned int)s << 16);
}

__device__ __forceinline__ void gload_lds16(const void* g, void* l) {
  __builtin_amdgcn_global_load_lds(
      (__attribute__((address_space(1))) void*)(uintptr_t)g,
      (__attribute__((address_space(3))) void*)l,
      16, 0, 0);
}

#define BARRIER() do { asm volatile("" ::: "memory"); __builtin_amdgcn_s_barrier(); asm volatile("" ::: "memory"); } while (0)
#define WAITVM(N) asm volatile("s_waitcnt vmcnt(" #N ")" ::: "memory")

// ---------------------------------------------------------------------------
// gemm8 (R12-verified, unchanged): 256x256 tile, BK=64, 8 waves, 5 barriers
// per K-tile, counted vmcnt(6), XOR-swizzled LDS, XCD-contiguous remap.
// MODE 0: bf16 out + f32 bias[n]
// MODE 1: fused row-softmax over N (requires nn==1, N==256): attn bf16 out
// ---------------------------------------------------------------------------
template <int MODE>
__global__ __launch_bounds__(512, 2) void gemm8(
    const unsigned short* __restrict__ A, const unsigned short* __restrict__ B,
    void* __restrict__ Cv, const void* __restrict__ aux, int N, int K,
    int nm, int nn, long sAB, long sBB, long sCB, long sXB, float scale)
{
  __shared__ __align__(16) char lds[131072];
  char* ldsc = lds;

  const int tid = threadIdx.x;
  const int lane = tid & 63;
  const int wid = tid >> 6;
  const int fr = lane & 15, fq = lane >> 4;

  const int nwg = gridDim.x;
  const int id = blockIdx.x;
  const int swz = (id & 7) * (nwg >> 3) + (id >> 3);
  const int per = nm * nn;
  const int t = swz / per;
  const int rem = swz - t * per;
  const int mi_ = rem / nn, ni_ = rem - mi_ * nn;
  const long bm = (long)mi_ * 256, bn = (long)ni_ * 256;

  const unsigned short* Ag = A + (long)t * sAB + bm * K;
  const unsigned short* Bg = B + (long)t * sBB + bn * K;
  const int NT = K >> 6;

  const unsigned short* aS[2][2];
  const unsigned short* bS[2][2];
#pragma unroll
  for (int p = 0; p < 2; ++p) {
    const int q = p * 512 + tid;
    const int lr = q >> 3, cs = q & 7;
    const int cl = cs ^ (lr & 7);
#pragma unroll
    for (int h = 0; h < 2; ++h) {
      const int gA = ((lr >> 6) << 7) | (h << 6) | (lr & 63);
      const int gB = ((lr >> 5) << 6) | (h << 5) | (lr & 31);
      aS[p][h] = Ag + (long)gA * K + cl * 8;
      bS[p][h] = Bg + (long)gB * K + cl * 8;
    }
  }

  const int c0 = ((fq ^ (fr & 3)) + ((fr >> 2) & 1) * 4) * 16;
  const int aRd = ((wid >> 2) * 64 + fr) * 128 + c0;
  const int bRd = ((wid & 3) * 32 + fr) * 128 + c0;

  f32x4 acc[2][2][4][2];
#pragma unroll
  for (int a = 0; a < 2; a++)
#pragma unroll
    for (int b = 0; b < 2; b++)
#pragma unroll
      for (int i = 0; i < 4; i++)
#pragma unroll
        for (int j = 0; j < 2; j++)
#pragma unroll
          for (int r = 0; r < 4; r++) acc[a][b][i][j][r] = 0.f;

  bf16x8 af0[4][2], af1[4][2], bf[2][2][2];

#define STAGE(srcArr, aoff, h, ktv, b) do {                                   \
  _Pragma("unroll")                                                           \
  for (int p = 0; p < 2; ++p)                                                 \
    gload_lds16(srcArr[p][h] + ((long)(ktv) << 6),                            \
                ldsc + (aoff) + ((b) << 16) + ((h) << 14) + (p << 13) + (wid << 10)); \
} while (0)

#define LDA(dst, mi, cub) do {                                                \
  _Pragma("unroll")                                                           \
  for (int i = 0; i < 4; ++i) {                                               \
    dst[i][0] = *(const bf16x8*)(ldsc + (cub) + (mi) * 16384 + aRd + i * 2048);        \
    dst[i][1] = *(const bf16x8*)(ldsc + (cub) + (mi) * 16384 + (aRd ^ 64) + i * 2048); \
  }                                                                           \
} while (0)

#define LDB(nj, cub) do {                                                     \
  _Pragma("unroll")                                                           \
  for (int j = 0; j < 2; ++j) {                                               \
    bf[nj][j][0] = *(const bf16x8*)(ldsc + 32768 + (cub) + (nj) * 16384 + bRd + j * 2048);        \
    bf[nj][j][1] = *(const bf16x8*)(ldsc + 32768 + (cub) + (nj) * 16384 + (bRd ^ 64) + j * 2048); \
  }                                                                           \
} while (0)

#define QUAD(AF, mi, nj) do {                                                 \
  __builtin_amdgcn_s_setprio(1);                                              \
  _Pragma("unroll")                                                           \
  for (int i = 0; i < 4; ++i)                                                 \
  _Pragma("unroll")                                                           \
  for (int j = 0; j < 2; ++j) {                                               \
    acc[mi][nj][i][j] = __builtin_amdgcn_mfma_f32_16x16x32_bf16(              \
        AF[i][0], bf[nj][j][0], acc[mi][nj][i][j], 0, 0, 0);                  \
    acc[mi][nj][i][j] = __builtin_amdgcn_mfma_f32_16x16x32_bf16(              \
        AF[i][1], bf[nj][j][1], acc[mi][nj][i][j], 0, 0, 0);                  \
  }                                                                           \
  __builtin_amdgcn_s_setprio(0);                                              \
} while (0)

  STAGE(aS, 0, 0, 0, 0);
  STAGE(bS, 32768, 0, 0, 0);
  STAGE(bS, 32768, 1, 0, 0);
  STAGE(aS, 0, 1, 0, 0);
  if (NT > 1) {
    STAGE(aS, 0, 0, 1, 1);
    STAGE(bS, 32768, 0, 1, 1);
    STAGE(bS, 32768, 1, 1, 1);
    WAITVM(6);
  } else {
    WAITVM(0);
  }
  BARRIER();

  for (int kt = 0; kt < NT; ++kt) {
    const int cur = kt & 1, nxt = cur ^ 1;
    const int cub = cur << 16;
    LDA(af0, 0, cub);
    LDB(0, cub);
    if (kt + 1 < NT) STAGE(aS, 0, 1, kt + 1, nxt);
    BARRIER();
    QUAD(af0, 0, 0);
    BARRIER();
    LDB(1, cub);
    LDA(af1, 1, cub);
    if (kt + 2 < NT) {
      STAGE(aS, 0, 0, kt + 2, cur);
      STAGE(bS, 32768, 0, kt + 2, cur);
    }
    BARRIER();
    QUAD(af0, 0, 1);
    QUAD(af1, 1, 0);
    BARRIER();
    if (kt + 2 < NT) {
      STAGE(bS, 32768, 1, kt + 2, cur);
      QUAD(af1, 1, 1);
      WAITVM(6);
    } else {
      QUAD(af1, 1, 1);
      WAITVM(0);
    }
    BARRIER();
  }

  if (MODE == 1) {
    float* red  = (float*)ldsc;            // [256][4]
    float* red2 = (float*)(ldsc + 4096);   // [256][4]
    const int wc = wid & 3;
    const int rbase = (wid >> 2) * 128;
#pragma unroll
    for (int mi = 0; mi < 2; ++mi)
#pragma unroll
      for (int i = 0; i < 4; ++i)
#pragma unroll
        for (int r = 0; r < 4; ++r) {
          float m = fmaxf(fmaxf(acc[mi][0][i][0][r], acc[mi][0][i][1][r]),
                          fmaxf(acc[mi][1][i][0][r], acc[mi][1][i][1][r]));
#pragma unroll
          for (int o = 1; o <= 8; o <<= 1) m = fmaxf(m, __shfl_xor(m, o));
          if (fr == 0) red[(rbase + mi * 64 + i * 16 + fq * 4 + r) * 4 + wc] = m;
        }
    BARRIER();
#pragma unroll
    for (int mi = 0; mi < 2; ++mi)
#pragma unroll
      for (int i = 0; i < 4; ++i)
#pragma unroll
        for (int r = 0; r < 4; ++r) {
          const int rl = rbase + mi * 64 + i * 16 + fq * 4 + r;
          f32x4 mm = *(f32x4*)&red[rl * 4];
          const float M = fmaxf(fmaxf(mm[0], mm[1]), fmaxf(mm[2], mm[3]));
          float s = 0.f;
#pragma unroll
          for (int nj = 0; nj < 2; ++nj)
#pragma unroll
            for (int j = 0; j < 2; ++j) {
              float e = __expf((acc[mi][nj][i][j][r] - M) * scale);
              acc[mi][nj][i][j][r] = e;
              s += e;
            }
#pragma unroll
          for (int o = 1; o <= 8; o <<= 1) s += __shfl_xor(s, o);
          if (fr == 0) red2[rl * 4 + wc] = s;
        }
    BARRIER();
    unsigned short* C = (unsigned short*)Cv + (long)t * sCB;
#pragma unroll
    for (int mi = 0; mi < 2; ++mi)
#pragma unroll
      for (int i = 0; i < 4; ++i)
#pragma unroll
        for (int r = 0; r < 4; ++r) {
          const int rl = rbase + mi * 64 + i * 16 + fq * 4 + r;
          f32x4 sv = *(f32x4*)&red2[rl * 4];
          const float inv = 1.0f / (sv[0] + sv[1] + sv[2] + sv[3]);
          const long gr = bm + rl;
#pragma unroll
          for (int nj = 0; nj < 2; ++nj)
#pragma unroll
            for (int j = 0; j < 2; ++j) {
              const long gcol = bn + wc * 64 + nj * 32 + j * 16 + fr;
              C[gr * N + gcol] = f2bf(acc[mi][nj][i][j][r] * inv);
            }
        }
  } else {
#pragma unroll
    for (int mi = 0; mi < 2; ++mi)
#pragma unroll
      for (int nj = 0; nj < 2; ++nj)
#pragma unroll
        for (int i = 0; i < 4; ++i) {
          const long grow0 = bm + (wid >> 2) * 128 + mi * 64 + i * 16 + fq * 4;
#pragma unroll
          for (int j = 0; j < 2; ++j) {
            const long gcol = bn + (wid & 3) * 64 + nj * 32 + j * 16 + fr;
            unsigned short* C = (unsigned short*)Cv + (long)t * sCB;
            const float bv = ((const float*)aux)[gcol];
#pragma unroll
            for (int r = 0; r < 4; ++r)
              C[(grow0 + r) * N + gcol] = f2bf(acc[mi][nj][i][j][r] + bv);
          }
        }
  }
#undef STAGE
#undef LDA
#undef LDB
#undef QUAD
}

// ---------------------------------------------------------------------------
// ctx_v2: out[t] = attn[t] @ slowT[t]^T + residual, specialized for K=256.
// Block = 128 rows x 128 cols. attn A-tile (128x256 bf16 = 64 KB) staged ONCE
// into LDS as 4 sub-buffers of [128 rows][128 B], XOR-chunk-swizzled via
// pre-swizzled global source + linear gload_lds dest (same algebra as gemm8).
// B (slowT) fragments loaded directly global->VGPR (L2-resident panel).
// One vmcnt(0) + one barrier per block. 8 waves (2m x 4n), wave = 64m x 32n.
// ---------------------------------------------------------------------------
__global__ __launch_bounds__(512, 2) void ctx_v2(
    const unsigned short* __restrict__ attn,   // [64][1024][256]
    const unsigned short* __restrict__ slowT,  // [64][1024][256]
    float* __restrict__ out,                   // [64][1024][1024]
    const unsigned short* __restrict__ resid)  // [64][1024][1024] bf16
{
  __shared__ __align__(16) char lds[65536];
  char* ldsc = lds;

  const int tid = threadIdx.x;
  const int lane = tid & 63;
  const int wid = tid >> 6;
  const int fr = lane & 15, fq = lane >> 4;

  // XCD-contiguous remap; ni fastest so A-tile stays L2-hot across neighbors.
  const int nwg = gridDim.x;                  // 4096
  const int id = blockIdx.x;
  const int swz = (id & 7) * (nwg >> 3) + (id >> 3);
  const int t = swz >> 6;
  const int rem = swz & 63;
  const int mi_ = rem >> 3, ni_ = rem & 7;
  const long bm = (long)mi_ * 128, bn = (long)ni_ * 128;

  const unsigned short* Ag = attn + (long)t * 262144 + bm * 256;
  const unsigned short* Bg = slowT + (long)t * 262144;

  // --- stage A: 4 sub-buffers x 16 KB; 2 gload16/thread/sub (p=0,1).
  // linear dest byte in sub = p*8192 + wid*1024 + lane*16
  //   -> row gRow = p*64 + wid*8 + (lane>>3), chunk cs = lane&7
  // source chunk cl = cs ^ (gRow&7)  (XOR swizzle, read side matches below)
  {
    const int gRow = wid * 8 + (lane >> 3);       // p=0 row; p=1 adds 64
    const int cs = lane & 7;
#pragma unroll
    for (int p = 0; p < 2; ++p) {
      const int r = p * 64 + gRow;
      const int cl = cs ^ (r & 7);
      const unsigned short* src = Ag + (long)r * 256 + cl * 8;
#pragma unroll
      for (int s = 0; s < 4; ++s)
        gload_lds16(src + s * 64,
                    ldsc + s * 16384 + p * 8192 + wid * 1024 + (lane & 63) * 16);
    }
  }

  // --- B fragments direct to regs: wave cols wn = (wid&3)*32, nj in {0,1}
  // B[n][k] frag for k-step kk: lane (fr,fq) -> row bn+wn+nj*16+fr, k kk*32+fq*8
  bf16x8 bB[2][8];
  {
    const long col0 = bn + (wid & 3) * 32 + fr;
#pragma unroll
    for (int nj = 0; nj < 2; ++nj) {
      const unsigned short* bp = Bg + (col0 + nj * 16) * 256 + fq * 8;
#pragma unroll
      for (int kk = 0; kk < 8; ++kk)
        bB[nj][kk] = *(const bf16x8*)(bp + kk * 32);
    }
  }

  WAITVM(0);
  BARRIER();

  // --- compute: wave rows = (wid>>2)*64 + mif*16 + fr (mif 0..3)
  f32x4 acc[4][2];
#pragma unroll
  for (int i = 0; i < 4; i++)
#pragma unroll
    for (int j = 0; j < 2; j++)
#pragma unroll
      for (int r = 0; r < 4; r++) acc[i][j][r] = 0.f;

  const int c0 = ((fq ^ (fr & 3)) + ((fr >> 2) & 1) * 4) * 16;  // chunk'(fq)
  const int rowb = ((wid >> 2) * 64 + fr) * 128 + c0;           // + mif*2048

#pragma unroll
  for (int kk = 0; kk < 8; ++kk) {
    const int sub = (kk >> 1) * 16384;
    const int flip = (kk & 1) ? 64 : 0;
    bf16x8 aF[4];
#pragma unroll
    for (int mif = 0; mif < 4; ++mif)
      aF[mif] = *(const bf16x8*)(ldsc + sub + ((rowb + mif * 2048) ^ flip));
    __builtin_amdgcn_s_setprio(1);
#pragma unroll
    for (int mif = 0; mif < 4; ++mif)
#pragma unroll
      for (int nj = 0; nj < 2; ++nj)
        acc[mif][nj] = __builtin_amdgcn_mfma_f32_16x16x32_bf16(
            aF[mif], bB[nj][kk], acc[mif][nj], 0, 0, 0);
    __builtin_amdgcn_s_setprio(0);
  }

  // --- epilogue: out = acc + residual (bf16), f32 store
  float* C = out + (long)t * 1048576;
  const unsigned short* X = resid + (long)t * 1048576;
#pragma unroll
  for (int mif = 0; mif < 4; ++mif) {
    const long grow0 = bm + (wid >> 2) * 64 + mif * 16 + fq * 4;
#pragma unroll
    for (int nj = 0; nj < 2; ++nj) {
      const long gcol = bn + (wid & 3) * 32 + nj * 16 + fr;
#pragma unroll
      for (int r = 0; r < 4; ++r) {
        const long idx = (grow0 + r) * 1024 + gcol;
        C[idx] = acc[mif][nj][r] + bf2f(X[idx]);
      }
    }
  }
}

__global__ __launch_bounds__(256) void convert_f32_bf16(
    const float* __restrict__ in, unsigned short* __restrict__ out, long n) {
  long i = ((long)blockIdx.x * 256 + threadIdx.x) * 4;
  long stride = (long)gridDim.x * 1024;
  for (; i < n; i += stride) {
    float4 v = *(const float4*)(in + i);
    ushort4 o;
    o.x = f2bf(v.x); o.y = f2bf(v.y); o.z = f2bf(v.z); o.w = f2bf(v.w);
    *(ushort4*)(out + i) = o;
  }
}

// both weight matrices in one dispatch: blocks [0,512) -> W1, [512,1024) -> W2
__global__ __launch_bounds__(256) void convert_weights(
    const float* __restrict__ in1, unsigned short* __restrict__ out1,
    const float* __restrict__ in2, unsigned short* __restrict__ out2) {
  const int half = blockIdx.x >> 9;
  const float* in = half ? in2 : in1;
  unsigned short* out = half ? out2 : out1;
  long i = ((long)(blockIdx.x & 511) * 256 + threadIdx.x) * 4;
  long stride = 512L * 1024;
  for (; i < 1048576L; i += stride) {
    float4 v = *(const float4*)(in + i);
    ushort4 o;
    o.x = f2bf(v.x); o.y = f2bf(v.y); o.z = f2bf(v.z); o.w = f2bf(v.w);
    *(ushort4*)(out + i) = o;
  }
}

// slow_feature [64][256][1024] f32 -> slowBf [t][k][d] bf16 AND slowT [t][d][k] bf16
__global__ __launch_bounds__(256) void convert_transpose_slow(
    const float* __restrict__ in, unsigned short* __restrict__ outR,
    unsigned short* __restrict__ outT) {
  __shared__ unsigned short tile[32][33];
  int t = blockIdx.z;
  int d0 = blockIdx.x * 32;
  int k0 = blockIdx.y * 32;
  const float* ip = in + (long)t * 256 * 1024;
  unsigned short* rp = outR + (long)t * 256 * 1024;
  unsigned short* tp = outT + (long)t * 1024 * 256;
  int tx = threadIdx.x & 31, ty = threadIdx.x >> 5;
#pragma unroll
  for (int p = 0; p < 4; p++) {
    int k = ty + p * 8;
    unsigned short b = f2bf(ip[(long)(k0 + k) * 1024 + d0 + tx]);
    tile[k][tx] = b;
    rp[(long)(k0 + k) * 1024 + d0 + tx] = b;
  }
  __syncthreads();
#pragma unroll
  for (int p = 0; p < 4; p++) {
    int d = ty + p * 8;
    tp[(long)(d0 + d) * 256 + k0 + tx] = tile[tx][d];
  }
}

extern "C" void kernel_launch(void* const* d_in, const int* in_sizes, int n_in,
                              void* d_out, int out_size, void* d_ws, size_t ws_size,
                              hipStream_t stream) {
  const float* fastF     = (const float*)d_in[0];  // [64,1024,1024]
  const float* slowF     = (const float*)d_in[1];  // [64,256,1024]
  const float* fastW     = (const float*)d_in[2];  // [1024,1024]
  const float* fast_bias = (const float*)d_in[3];  // [1024]
  const float* slowW     = (const float*)d_in[4];  // [1024,1024]
  const float* slow_bias = (const float*)d_in[5];  // [1024]
  float* out = (float*)d_out;

  char* ws = (char*)d_ws;
  unsigned short* fastBf  = (unsigned short*)(ws);
  unsigned short* fastKey = (unsigned short*)(ws + 134217728L);
  unsigned short* slowBf  = (unsigned short*)(ws + 268435456L);
  unsigned short* attnBf  = (unsigned short*)(ws + 268435456L);  // reuses slowBf
  unsigned short* slowT   = (unsigned short*)(ws + 301989888L);
  unsigned short* slowKey = (unsigned short*)(ws + 335544320L);
  unsigned short* fWb     = (unsigned short*)(ws + 369098752L);
  unsigned short* sWb     = (unsigned short*)(ws + 371195904L);

  convert_f32_bf16<<<2048, 256, 0, stream>>>(fastF, fastBf, 67108864L);
  convert_weights<<<1024, 256, 0, stream>>>(fastW, fWb, slowW, sWb);
  convert_transpose_slow<<<dim3(32, 8, 64), 256, 0, stream>>>(slowF, slowBf, slowT);

  // slow_key = slow @ slowW^T + slow_b : M=16384, N=1024, K=1024 (NT=16)
  gemm8<0><<<64 * 4, 512, 0, stream>>>(slowBf, sWb, slowKey, slow_bias,
      1024, 1024, 64, 4, 0, 0, 0, 0, 1.f);
  // fast_key = fast @ fastW^T + fast_b : M=65536, N=1024, K=1024 (NT=16)
  gemm8<0><<<256 * 4, 512, 0, stream>>>(fastBf, fWb, fastKey, fast_bias,
      1024, 1024, 256, 4, 0, 0, 0, 0, 1.f);
  // attn[t] = softmax(fast_key[t] @ slow_key[t]^T / 32) : M=1024, N=256, K=1024 (NT=16)
  gemm8<1><<<4 * 1 * 64, 512, 0, stream>>>(fastKey, slowKey, attnBf, nullptr,
      256, 1024, 4, 1, 1048576L, 262144L, 262144L, 0, 0.03125f);
  // out[t] = attn[t] @ slow_T[t]^T + bf16(fast[t]) : specialized K=256 kernel
  ctx_v2<<<4096, 512, 0, stream>>>(attnBf, slowT, out, fastBf);
}

// Round 14
// 472.833 us; speedup vs baseline: 1.0498x; 1.0498x over previous
//
#include <hip/hip_runtime.h>
#include <stdint.h>

typedef __attribute__((ext_vector_type(8))) short bf16x8;
typedef __attribute__((ext_vector_type(4))) float f32x4;

__device__ __forceinline__ unsigned short f2bf(float f) {
  unsigned int u = __builtin_bit_cast(unsigned int, f);
  u += 0x7FFFu + ((u >> 16) & 1u);
  return (unsigned short)(u >> 16);
}

__device__ __forceinline__ float bf2f(unsigned short s) {
  return __builtin_bit_cast(float, (unsigned int)s << 16);
}

__device__ __forceinline__ void gload_lds16(const void* g, void* l) {
  __builtin_amdgcn_global_load_lds(
      (__attribute__((address_space(1))) void*)(uintptr_t)g,
      (__attribute__((address_space(3))) void*)l,
      16, 0, 0);
}

#define BARRIER() do { asm volatile("" ::: "memory"); __builtin_amdgcn_s_barrier(); asm volatile("" ::: "memory"); } while (0)
#define WAITVM(N) asm volatile("s_waitcnt vmcnt(" #N ")" ::: "memory")

// ---------------------------------------------------------------------------
// 256x256 tile, BK=64, 8 waves (2M x 4N), counted vmcnt, XOR-swizzled LDS
// (chunk c' = c ^ (row&7)), XCD-contiguous block remap. 5 barriers/K-tile
// (P1+P2 merged, split af0/af1 register sets). R12-verified configuration.
// C[m,n] = sum_k A[m,k]*B[n,k]. A: MxK bf16 rowmajor, B: NxK bf16 rowmajor.
// MODE 0: bf16 out + f32 bias[n]
// MODE 1: fused row-softmax over N (requires nn==1, N==256): attn bf16 out
// MODE 2: f32 out + bf16 aux (residual)
// ---------------------------------------------------------------------------
template <int MODE>
__global__ __launch_bounds__(512, 2) void gemm8(
    const unsigned short* __restrict__ A, const unsigned short* __restrict__ B,
    void* __restrict__ Cv, const void* __restrict__ aux, int N, int K,
    int nm, int nn, long sAB, long sBB, long sCB, long sXB, float scale)
{
  __shared__ __align__(16) char lds[131072];
  char* ldsc = lds;

  const int tid = threadIdx.x;
  const int lane = tid & 63;
  const int wid = tid >> 6;
  const int fr = lane & 15, fq = lane >> 4;

  const int nwg = gridDim.x;                 // divisible by 8 for all our shapes
  const int id = blockIdx.x;
  const int swz = (id & 7) * (nwg >> 3) + (id >> 3);
  const int per = nm * nn;
  const int t = swz / per;
  const int rem = swz - t * per;
  const int mi_ = rem / nn, ni_ = rem - mi_ * nn;
  const long bm = (long)mi_ * 256, bn = (long)ni_ * 256;

  const unsigned short* Ag = A + (long)t * sAB + bm * K;
  const unsigned short* Bg = B + (long)t * sBB + bn * K;
  const int NT = K >> 6;

  // --- staging source pointers (pre-swizzled global source, linear LDS dest)
  const unsigned short* aS[2][2];
  const unsigned short* bS[2][2];
#pragma unroll
  for (int p = 0; p < 2; ++p) {
    const int q = p * 512 + tid;
    const int lr = q >> 3, cs = q & 7;
    const int cl = cs ^ (lr & 7);
#pragma unroll
    for (int h = 0; h < 2; ++h) {
      const int gA = ((lr >> 6) << 7) | (h << 6) | (lr & 63);
      const int gB = ((lr >> 5) << 6) | (h << 5) | (lr & 31);
      aS[p][h] = Ag + (long)gA * K + cl * 8;
      bS[p][h] = Bg + (long)gB * K + cl * 8;
    }
  }

  // --- swizzled ds_read byte offsets (within a half): row*128 + chunk'*16
  const int c0 = ((fq ^ (fr & 3)) + ((fr >> 2) & 1) * 4) * 16;   // ks=0 chunk
  const int aRd = ((wid >> 2) * 64 + fr) * 128 + c0;  // + mi*16384 + i*2048 (^64 ks=1)
  const int bRd = ((wid & 3) * 32 + fr) * 128 + c0;   // + nj*16384 + j*2048 (^64 ks=1)

  f32x4 acc[2][2][4][2];
#pragma unroll
  for (int a = 0; a < 2; a++)
#pragma unroll
    for (int b = 0; b < 2; b++)
#pragma unroll
      for (int i = 0; i < 4; i++)
#pragma unroll
        for (int j = 0; j < 2; j++)
#pragma unroll
          for (int r = 0; r < 4; r++) acc[a][b][i][j][r] = 0.f;

  bf16x8 af0[4][2], af1[4][2], bf[2][2][2];

// stage one half-tile (2 x global_load_lds per thread). aoff: 0=A, 32768=B.
#define STAGE(srcArr, aoff, h, ktv, b) do {                                   \
  _Pragma("unroll")                                                           \
  for (int p = 0; p < 2; ++p)                                                 \
    gload_lds16(srcArr[p][h] + ((long)(ktv) << 6),                            \
                ldsc + (aoff) + ((b) << 16) + ((h) << 14) + (p << 13) + (wid << 10)); \
} while (0)

#define LDA(dst, mi, cub) do {                                                \
  _Pragma("unroll")                                                           \
  for (int i = 0; i < 4; ++i) {                                               \
    dst[i][0] = *(const bf16x8*)(ldsc + (cub) + (mi) * 16384 + aRd + i * 2048);        \
    dst[i][1] = *(const bf16x8*)(ldsc + (cub) + (mi) * 16384 + (aRd ^ 64) + i * 2048); \
  }                                                                           \
} while (0)

#define LDB(nj, cub) do {                                                     \
  _Pragma("unroll")                                                           \
  for (int j = 0; j < 2; ++j) {                                               \
    bf[nj][j][0] = *(const bf16x8*)(ldsc + 32768 + (cub) + (nj) * 16384 + bRd + j * 2048);        \
    bf[nj][j][1] = *(const bf16x8*)(ldsc + 32768 + (cub) + (nj) * 16384 + (bRd ^ 64) + j * 2048); \
  }                                                                           \
} while (0)

#define QUAD(AF, mi, nj) do {                                                 \
  __builtin_amdgcn_s_setprio(1);                                              \
  _Pragma("unroll")                                                           \
  for (int i = 0; i < 4; ++i)                                                 \
  _Pragma("unroll")                                                           \
  for (int j = 0; j < 2; ++j) {                                               \
    acc[mi][nj][i][j] = __builtin_amdgcn_mfma_f32_16x16x32_bf16(              \
        AF[i][0], bf[nj][j][0], acc[mi][nj][i][j], 0, 0, 0);                  \
    acc[mi][nj][i][j] = __builtin_amdgcn_mfma_f32_16x16x32_bf16(              \
        AF[i][1], bf[nj][j][1], acc[mi][nj][i][j], 0, 0, 0);                  \
  }                                                                           \
  __builtin_amdgcn_s_setprio(0);                                              \
} while (0)

  // --- prologue: kt0 {A0,B0,B1,A1} -> buf0; kt1 {A0,B0,B1} -> buf1
  STAGE(aS, 0, 0, 0, 0);
  STAGE(bS, 32768, 0, 0, 0);
  STAGE(bS, 32768, 1, 0, 0);
  STAGE(aS, 0, 1, 0, 0);
  if (NT > 1) {
    STAGE(aS, 0, 0, 1, 1);
    STAGE(bS, 32768, 0, 1, 1);
    STAGE(bS, 32768, 1, 1, 1);
    WAITVM(6);
  } else {
    WAITVM(0);
  }
  BARRIER();

  for (int kt = 0; kt < NT; ++kt) {
    const int cur = kt & 1, nxt = cur ^ 1;
    const int cub = cur << 16;
    // P0: read A0->af0, B0->bf[0]; prefetch kt+1's A1 -> nxt
    LDA(af0, 0, cub);
    LDB(0, cub);
    if (kt + 1 < NT) STAGE(aS, 0, 1, kt + 1, nxt);
    BARRIER();
    QUAD(af0, 0, 0);
    BARRIER();
    // P12 (merged): read B1->bf[1], A1->af1; prefetch kt+2's A0,B0 -> cur
    LDB(1, cub);
    LDA(af1, 1, cub);
    if (kt + 2 < NT) {
      STAGE(aS, 0, 0, kt + 2, cur);
      STAGE(bS, 32768, 0, kt + 2, cur);
    }
    BARRIER();
    QUAD(af0, 0, 1);
    QUAD(af1, 1, 0);
    BARRIER();
    // P3: prefetch kt+2's B1 -> cur
    if (kt + 2 < NT) {
      STAGE(bS, 32768, 1, kt + 2, cur);
      QUAD(af1, 1, 1);
      WAITVM(6);           // keep 3 half-tiles (kt+2 A0,B0,B1) in flight
    } else {
      QUAD(af1, 1, 1);
      WAITVM(0);
    }
    BARRIER();
  }

  // --- epilogue
  if (MODE == 1) {
    // fused row-softmax of (acc*scale) over the full N=256 row; attn bf16 out.
    float* red  = (float*)ldsc;            // [256][4]
    float* red2 = (float*)(ldsc + 4096);   // [256][4]
    const int wc = wid & 3;
    const int rbase = (wid >> 2) * 128;
#pragma unroll
    for (int mi = 0; mi < 2; ++mi)
#pragma unroll
      for (int i = 0; i < 4; ++i)
#pragma unroll
        for (int r = 0; r < 4; ++r) {
          float m = fmaxf(fmaxf(acc[mi][0][i][0][r], acc[mi][0][i][1][r]),
                          fmaxf(acc[mi][1][i][0][r], acc[mi][1][i][1][r]));
#pragma unroll
          for (int o = 1; o <= 8; o <<= 1) m = fmaxf(m, __shfl_xor(m, o));
          if (fr == 0) red[(rbase + mi * 64 + i * 16 + fq * 4 + r) * 4 + wc] = m;
        }
    BARRIER();
#pragma unroll
    for (int mi = 0; mi < 2; ++mi)
#pragma unroll
      for (int i = 0; i < 4; ++i)
#pragma unroll
        for (int r = 0; r < 4; ++r) {
          const int rl = rbase + mi * 64 + i * 16 + fq * 4 + r;
          f32x4 mm = *(f32x4*)&red[rl * 4];
          const float M = fmaxf(fmaxf(mm[0], mm[1]), fmaxf(mm[2], mm[3]));
          float s = 0.f;
#pragma unroll
          for (int nj = 0; nj < 2; ++nj)
#pragma unroll
            for (int j = 0; j < 2; ++j) {
              float e = __expf((acc[mi][nj][i][j][r] - M) * scale);
              acc[mi][nj][i][j][r] = e;
              s += e;
            }
#pragma unroll
          for (int o = 1; o <= 8; o <<= 1) s += __shfl_xor(s, o);
          if (fr == 0) red2[rl * 4 + wc] = s;
        }
    BARRIER();
    unsigned short* C = (unsigned short*)Cv + (long)t * sCB;
#pragma unroll
    for (int mi = 0; mi < 2; ++mi)
#pragma unroll
      for (int i = 0; i < 4; ++i)
#pragma unroll
        for (int r = 0; r < 4; ++r) {
          const int rl = rbase + mi * 64 + i * 16 + fq * 4 + r;
          f32x4 sv = *(f32x4*)&red2[rl * 4];
          const float inv = 1.0f / (sv[0] + sv[1] + sv[2] + sv[3]);
          const long gr = bm + rl;
#pragma unroll
          for (int nj = 0; nj < 2; ++nj)
#pragma unroll
            for (int j = 0; j < 2; ++j) {
              const long gcol = bn + wc * 64 + nj * 32 + j * 16 + fr;
              C[gr * N + gcol] = f2bf(acc[mi][nj][i][j][r] * inv);
            }
        }
  } else {
#pragma unroll
    for (int mi = 0; mi < 2; ++mi)
#pragma unroll
      for (int nj = 0; nj < 2; ++nj)
#pragma unroll
        for (int i = 0; i < 4; ++i) {
          const long grow0 = bm + (wid >> 2) * 128 + mi * 64 + i * 16 + fq * 4;
#pragma unroll
          for (int j = 0; j < 2; ++j) {
            const long gcol = bn + (wid & 3) * 64 + nj * 32 + j * 16 + fr;
            if (MODE == 0) {
              unsigned short* C = (unsigned short*)Cv + (long)t * sCB;
              const float bv = ((const float*)aux)[gcol];
#pragma unroll
              for (int r = 0; r < 4; ++r)
                C[(grow0 + r) * N + gcol] = f2bf(acc[mi][nj][i][j][r] + bv);
            } else {
              float* C = (float*)Cv + (long)t * sCB;
              const unsigned short* X = (const unsigned short*)aux + (long)t * sXB;
#pragma unroll
              for (int r = 0; r < 4; ++r) {
                const long idx = (grow0 + r) * N + gcol;
                C[idx] = acc[mi][nj][i][j][r] + bf2f(X[idx]);
              }
            }
          }
        }
  }
#undef STAGE
#undef LDA
#undef LDB
#undef QUAD
}

__global__ __launch_bounds__(256) void convert_f32_bf16(
    const float* __restrict__ in, unsigned short* __restrict__ out, long n) {
  long i = ((long)blockIdx.x * 256 + threadIdx.x) * 4;
  long stride = (long)gridDim.x * 1024;
  for (; i < n; i += stride) {
    float4 v = *(const float4*)(in + i);
    ushort4 o;
    o.x = f2bf(v.x); o.y = f2bf(v.y); o.z = f2bf(v.z); o.w = f2bf(v.w);
    *(ushort4*)(out + i) = o;
  }
}

// both weight matrices in one dispatch: blocks [0,512) -> W1, [512,1024) -> W2
__global__ __launch_bounds__(256) void convert_weights(
    const float* __restrict__ in1, unsigned short* __restrict__ out1,
    const float* __restrict__ in2, unsigned short* __restrict__ out2) {
  const int half = blockIdx.x >> 9;
  const float* in = half ? in2 : in1;
  unsigned short* out = half ? out2 : out1;
  long i = ((long)(blockIdx.x & 511) * 256 + threadIdx.x) * 4;
  long stride = 512L * 1024;
  for (; i < 1048576L; i += stride) {
    float4 v = *(const float4*)(in + i);
    ushort4 o;
    o.x = f2bf(v.x); o.y = f2bf(v.y); o.z = f2bf(v.z); o.w = f2bf(v.w);
    *(ushort4*)(out + i) = o;
  }
}

// slow_feature [64][256][1024] f32 -> slowBf [t][k][d] bf16 AND slowT [t][d][k] bf16
__global__ __launch_bounds__(256) void convert_transpose_slow(
    const float* __restrict__ in, unsigned short* __restrict__ outR,
    unsigned short* __restrict__ outT) {
  __shared__ unsigned short tile[32][33];
  int t = blockIdx.z;
  int d0 = blockIdx.x * 32;
  int k0 = blockIdx.y * 32;
  const float* ip = in + (long)t * 256 * 1024;
  unsigned short* rp = outR + (long)t * 256 * 1024;
  unsigned short* tp = outT + (long)t * 1024 * 256;
  int tx = threadIdx.x & 31, ty = threadIdx.x >> 5;
#pragma unroll
  for (int p = 0; p < 4; p++) {
    int k = ty + p * 8;
    unsigned short b = f2bf(ip[(long)(k0 + k) * 1024 + d0 + tx]);
    tile[k][tx] = b;
    rp[(long)(k0 + k) * 1024 + d0 + tx] = b;
  }
  __syncthreads();
#pragma unroll
  for (int p = 0; p < 4; p++) {
    int d = ty + p * 8;
    tp[(long)(d0 + d) * 256 + k0 + tx] = tile[tx][d];
  }
}

extern "C" void kernel_launch(void* const* d_in, const int* in_sizes, int n_in,
                              void* d_out, int out_size, void* d_ws, size_t ws_size,
                              hipStream_t stream) {
  const float* fastF     = (const float*)d_in[0];  // [64,1024,1024]
  const float* slowF     = (const float*)d_in[1];  // [64,256,1024]
  const float* fastW     = (const float*)d_in[2];  // [1024,1024]
  const float* fast_bias = (const float*)d_in[3];  // [1024]
  const float* slowW     = (const float*)d_in[4];  // [1024,1024]
  const float* slow_bias = (const float*)d_in[5];  // [1024]
  float* out = (float*)d_out;

  char* ws = (char*)d_ws;
  // layout: fastBf [0,128M) alive until ctx (residual); fastKey [128M,256M);
  // attnBf [256M,288M) over dead slowBf; slowT [288M,320M);
  // slowKey [320M,352M); weights at 352M+.
  unsigned short* fastBf  = (unsigned short*)(ws);
  unsigned short* fastKey = (unsigned short*)(ws + 134217728L);
  unsigned short* slowBf  = (unsigned short*)(ws + 268435456L);
  unsigned short* attnBf  = (unsigned short*)(ws + 268435456L);  // reuses slowBf
  unsigned short* slowT   = (unsigned short*)(ws + 301989888L);
  unsigned short* slowKey = (unsigned short*)(ws + 335544320L);
  unsigned short* fWb     = (unsigned short*)(ws + 369098752L);
  unsigned short* sWb     = (unsigned short*)(ws + 371195904L);

  convert_f32_bf16<<<2048, 256, 0, stream>>>(fastF, fastBf, 67108864L);
  convert_weights<<<1024, 256, 0, stream>>>(fastW, fWb, slowW, sWb);
  convert_transpose_slow<<<dim3(32, 8, 64), 256, 0, stream>>>(slowF, slowBf, slowT);

  // slow_key = slow @ slowW^T + slow_b : M=16384, N=1024, K=1024 (NT=16)
  gemm8<0><<<64 * 4, 512, 0, stream>>>(slowBf, sWb, slowKey, slow_bias,
      1024, 1024, 64, 4, 0, 0, 0, 0, 1.f);
  // fast_key = fast @ fastW^T + fast_b : M=65536, N=1024, K=1024 (NT=16)
  gemm8<0><<<256 * 4, 512, 0, stream>>>(fastBf, fWb, fastKey, fast_bias,
      1024, 1024, 256, 4, 0, 0, 0, 0, 1.f);
  // attn[t] = softmax(fast_key[t] @ slow_key[t]^T / 32) : M=1024, N=256, K=1024 (NT=16)
  gemm8<1><<<4 * 1 * 64, 512, 0, stream>>>(fastKey, slowKey, attnBf, nullptr,
      256, 1024, 4, 1, 1048576L, 262144L, 262144L, 0, 0.03125f);
  // out[t] = attn[t] @ slow_T[t]^T + bf16(fast[t]) : M=1024, N=1024, K=256 (NT=4)
  gemm8<2><<<4 * 4 * 64, 512, 0, stream>>>(attnBf, slowT, out, fastBf,
      1024, 256, 4, 4, 262144L, 262144L, 1048576L, 1048576L, 1.f);
}